// Round 5
// baseline (501.192 us; speedup 1.0000x reference)
//
#include <hip/hip_runtime.h>
#include <cstdint>

typedef __attribute__((ext_vector_type(8))) short bf16x8;
typedef __attribute__((ext_vector_type(4))) float f32x4;
typedef unsigned short u16;
typedef uint32_t u32;

#define HW56 56
#define HWSQ 3136       // 56*56
#define MTOT 200704     // 64*3136
#define CCH 128
#define BM 128
#define NSTEP 18        // 9 taps * 2 K-halves (BK=64)
#define NBLK (MTOT / BM)        // 1568 = 8 * 196
#define NB_PER_XCD (NBLK / 8)   // 196

__device__ __forceinline__ u16 f2bf(float f) {
  u32 u = __builtin_bit_cast(u32, f);
  u = (u + 0x7fffu + ((u >> 16) & 1u)) >> 16;   // RNE
  return (u16)u;
}
__device__ __forceinline__ float bf2f(u16 h) {
  return __builtin_bit_cast(float, (u32)h << 16);
}
__device__ __forceinline__ void gload16(const void* g, void* l) {
  __builtin_amdgcn_global_load_lds((const __attribute__((address_space(1))) void*)g,
                                   (__attribute__((address_space(3))) void*)l, 16, 0, 0);
}

// ---------- pack x: NCHW f32 -> NHWC bf16, LDS-transposed so BOTH sides coalesce ----
__global__ __launch_bounds__(256) void pack_x_kernel(const float* __restrict__ x,
                                                     u16* __restrict__ xb) {
  __shared__ u16 t[128 * 65];                 // [c][pos], stride 65 (bank-friendly)
  const int tid = threadIdx.x;
  const int lane = tid & 63, wv = tid >> 6;
  const int p0 = blockIdx.x * 64;             // 64 pos, one image (3136 % 64 == 0)
  const int n = p0 / HWSQ, hw0 = p0 % HWSQ;
  const float* src = x + (size_t)(n * CCH) * HWSQ + hw0;
#pragma unroll
  for (int k = 0; k < 32; ++k) {              // coalesced 256B reads per instr
    const int c = wv * 32 + k;
    t[c * 65 + lane] = f2bf(src[(size_t)c * HWSQ + lane]);
  }
  __syncthreads();
  u16* dst = xb + (size_t)p0 * CCH;
#pragma unroll
  for (int it = 0; it < 4; ++it) {            // coalesced 1KB writes per wave-instr
    const int u = it * 256 + tid;
    const int pos = u >> 4, ch0 = (u & 15) * 8;
    u32 vv[4];
#pragma unroll
    for (int q = 0; q < 4; ++q) {
      const u16 a = t[(ch0 + 2 * q) * 65 + pos];
      const u16 b = t[(ch0 + 2 * q + 1) * 65 + pos];
      vv[q] = (u32)a | ((u32)b << 16);
    }
    uint4 v; v.x = vv[0]; v.y = vv[1]; v.z = vv[2]; v.w = vv[3];
    *(uint4*)(dst + (size_t)pos * CCH + ch0) = v;
  }
}

// ---------- pack weights: fold BN scale, [O][I][3][3] f32 -> [tap][oc][ic] bf16 ----------
__global__ __launch_bounds__(256) void pack_w_kernel(
    const float* __restrict__ w1, const float* __restrict__ w2,
    const float* __restrict__ g1, const float* __restrict__ be1,
    const float* __restrict__ mu1, const float* __restrict__ va1,
    const float* __restrict__ g2, const float* __restrict__ be2,
    const float* __restrict__ mu2, const float* __restrict__ va2,
    u16* __restrict__ w1p, u16* __restrict__ w2p,
    float* __restrict__ b1, float* __restrict__ b2, float* __restrict__ zp) {
  const int idx = blockIdx.x * 256 + threadIdx.x;   // grid = 294912/256
  if (idx < 2 * 147456) {
    const int which = idx >= 147456;
    const int j = which ? idx - 147456 : idx;
    const int t = j >> 14;            // tap 0..8
    const int oc = (j >> 7) & 127;
    const int ic = j & 127;
    const float* w = which ? w2 : w1;
    const float* gg = which ? g2 : g1;
    const float* va = which ? va2 : va1;
    const float s = gg[oc] * rsqrtf(va[oc] + 1e-5f);
    const float val = w[(size_t)(oc * 128 + ic) * 9 + t] * s;
    (which ? w2p : w1p)[j] = f2bf(val);
  }
  if (blockIdx.x == 0) {
    const int t = threadIdx.x;
    if (t < 128) {
      const float s1 = g1[t] * rsqrtf(va1[t] + 1e-5f);
      b1[t] = be1[t] - mu1[t] * s1;
      const float s2 = g2[t] * rsqrtf(va2[t] + 1e-5f);
      b2[t] = be2[t] - mu2[t] * s2;
    }
    if (t < 64) zp[t] = 0.f;          // 256B zero page (ws is re-poisoned each launch)
  }
}

// ---------- implicit-GEMM conv 3x3 (pad=1) with fused BN(+ReLU)(+residual) ----------
// A (activations): global->LDS staged, double-buffered, XOR-swizzled rows.
// B (weights, 288KB L2-resident): global->VGPR direct, no LDS (cache-fit rule).
// Sync: round-3 structure — single __syncthreads per K-step, compiler-scheduled.
template <int PASS>
__global__ __launch_bounds__(256, 3) void conv_mfma(
    const u16* __restrict__ src, const u16* __restrict__ wp,
    const float* __restrict__ bias, const u16* __restrict__ resid,
    u16* __restrict__ outb, float* __restrict__ outf,
    const char* __restrict__ zp) {
  // LDS: A0 | A1 (16KB each). Rows of 128B (64 ic bf16); slot s of row r holds
  // source 16B-group s^(r&7).
  __shared__ __align__(1024) char lds[32768];
  const int tid = threadIdx.x;
  const int wave = tid >> 6, lane = tid & 63;
  // T1: XCD-chunked bijective swizzle (1568 % 8 == 0)
  const int bid = blockIdx.x;
  const int swz = (bid & 7) * NB_PER_XCD + (bid >> 3);
  const int m0 = swz * BM;
  const int wm = wave >> 1, wn = wave & 1;    // 2x2 wave grid, 64x64 tile each

  // A staging state: 4 rows (8-row groups), one 16B group each.
  const int g = lane & 7;
  int ah[4], aw[4];
  long long aoff[4];
#pragma unroll
  for (int i = 0; i < 4; ++i) {
    const int r = wave * 32 + i * 8 + (lane >> 3);  // row 0..127
    const int pos = m0 + r;
    const int hw = pos % HWSQ;
    ah[i] = hw / HW56;
    aw[i] = hw % HW56;
    const int gsw = g ^ (r & 7);                    // pre-swizzled source group
    aoff[i] = (long long)pos * 256 + gsw * 16;      // NHWC row = 256B
  }
  const char* srcb = (const char*)src;
  // B direct-load base: row = wn*64 + (lane&15), k-sub-group (lane>>4)
  const char* wbase = (const char*)wp + (wn * 64 + (lane & 15)) * 256 + (lane >> 4) * 16;

  auto stageA = [&](int buf, int s) {               // 4 gload16 per thread
    const int t = s >> 1, kh = s & 1;
    const int dyo = t / 3 - 1, dxo = t % 3 - 1;
    const long long adelta = (long long)(dyo * HW56 + dxo) * 256 + kh * 128;
    char* ldsA = lds + buf * 16384;
#pragma unroll
    for (int i = 0; i < 4; ++i) {
      const int hh = ah[i] + dyo, ww = aw[i] + dxo;
      const bool valid = ((unsigned)hh < 56u) & ((unsigned)ww < 56u);
      const char* ap = valid ? (srcb + aoff[i] + adelta) : zp;  // zero-pad via zero page
      gload16(ap, ldsA + (wave * 32 + i * 8) * 128);            // LDS dest wave-uniform
    }
  };

  f32x4 acc[4][4];
#pragma unroll
  for (int m = 0; m < 4; ++m)
#pragma unroll
    for (int n = 0; n < 4; ++n) {
      f32x4 z = {0.f, 0.f, 0.f, 0.f};
      acc[m][n] = z;
    }

  stageA(0, 0);
  __syncthreads();
#pragma unroll
  for (int s = 0; s < NSTEP; ++s) {
    const int cur = s & 1;
    const int t = s >> 1, kh = s & 1;
    // B frags for THIS step: 8 global_load_dwordx4, L2-hit (issued before A-stage
    // so the auto-waitcnt on B-use doesn't drain the younger A-stage loads).
    bf16x8 b[4][2];
#pragma unroll
    for (int n = 0; n < 4; ++n)
#pragma unroll
      for (int ks = 0; ks < 2; ++ks)
        b[n][ks] = *(const bf16x8*)(wbase + t * 32768 + kh * 128 + n * 4096 + ks * 64);
    if (s + 1 < NSTEP) stageA(cur ^ 1, s + 1);     // prefetch next A tile
    // A frags from LDS (swizzled ds_read_b128) + MFMA
    {
      const char* ldsA = lds + cur * 16384;
      bf16x8 a[4][2];
#pragma unroll
      for (int m = 0; m < 4; ++m) {
        const int row = wm * 64 + m * 16 + (lane & 15);
        const char* rp = ldsA + row * 128;
        const int sw = row & 7;
#pragma unroll
        for (int ks = 0; ks < 2; ++ks) {
          const int gg = ks * 4 + (lane >> 4);              // k-group: ks*32 + (lane>>4)*8
          a[m][ks] = *(const bf16x8*)(rp + ((gg ^ sw) << 4));
        }
      }
#pragma unroll
      for (int ks = 0; ks < 2; ++ks)
#pragma unroll
        for (int m = 0; m < 4; ++m)
#pragma unroll
          for (int n = 0; n < 4; ++n)
            acc[m][n] = __builtin_amdgcn_mfma_f32_16x16x32_bf16(a[m][ks], b[n][ks],
                                                                acc[m][n], 0, 0, 0);
    }
    __syncthreads();                               // drains vmcnt+lgkmcnt (m97 structure)
  }

  if (PASS == 1) {
#pragma unroll
    for (int nf = 0; nf < 4; ++nf) {
      const int oc = wn * 64 + nf * 16 + (lane & 15);
      const float bb = bias[oc];
#pragma unroll
      for (int m = 0; m < 4; ++m) {
        const int pbase = m0 + wm * 64 + m * 16 + (lane >> 4) * 4;
#pragma unroll
        for (int r = 0; r < 4; ++r) {
          float v = acc[m][nf][r] + bb;
          v = fmaxf(v, 0.f);
          outb[(size_t)(pbase + r) * CCH + oc] = f2bf(v);
        }
      }
    }
  } else {
    // epilogue: bias + residual + relu, then per-wave LDS transpose -> coalesced NCHW f32
    float* tl = (float*)(lds + wave * 4352);     // [64][17] f32, wave-private (17KB < 32KB)
    const int posr = m0 + wm * 64 + lane;
    const int nimg = posr / HWSQ, hwr = posr % HWSQ;
#pragma unroll
    for (int nf = 0; nf < 4; ++nf) {
      const int oc = wn * 64 + nf * 16 + (lane & 15);
      const float bb = bias[oc];
#pragma unroll
      for (int m = 0; m < 4; ++m) {
#pragma unroll
        for (int r = 0; r < 4; ++r) {
          const int row = m * 16 + (lane >> 4) * 4 + r;
          const int pos = m0 + wm * 64 + row;
          const float rv = bf2f(resid[(size_t)pos * CCH + oc]);
          float v = acc[m][nf][r] + bb + rv;
          tl[row * 17 + (lane & 15)] = fmaxf(v, 0.f);
        }
      }
      // compiler inserts lgkmcnt waits for the within-wave LDS RAW/WAR here
#pragma unroll
      for (int oci = 0; oci < 16; ++oci) {
        const float v = tl[lane * 17 + oci];
        const int oc2 = wn * 64 + nf * 16 + oci;
        outf[(size_t)(nimg * CCH + oc2) * HWSQ + hwr] = v;   // 64 consecutive hw per store
      }
    }
  }
}

extern "C" void kernel_launch(void* const* d_in, const int* in_sizes, int n_in,
                              void* d_out, int out_size, void* d_ws, size_t ws_size,
                              hipStream_t stream) {
  const float* x = (const float*)d_in[0];
  const float* w1 = (const float*)d_in[1];
  const float* w2 = (const float*)d_in[2];
  const float* g1 = (const float*)d_in[3];
  const float* be1 = (const float*)d_in[4];
  const float* mu1 = (const float*)d_in[5];
  const float* va1 = (const float*)d_in[6];
  const float* g2 = (const float*)d_in[7];
  const float* be2 = (const float*)d_in[8];
  const float* mu2 = (const float*)d_in[9];
  const float* va2 = (const float*)d_in[10];

  char* ws = (char*)d_ws;
  u16* xb  = (u16*)(ws + 0);                    // 200704*128*2 = 51,380,224 B
  u16* o1b = (u16*)(ws + 51380224);             // 51,380,224 B
  u16* w1p = (u16*)(ws + 102760448);            // 294,912 B
  u16* w2p = (u16*)(ws + 103055360);            // 294,912 B
  float* b1 = (float*)(ws + 103350272);         // 512 B
  float* b2 = (float*)(ws + 103350784);         // 512 B
  float* zp = (float*)(ws + 103351296);         // 256 B zero page

  pack_x_kernel<<<MTOT / 64, 256, 0, stream>>>(x, xb);
  pack_w_kernel<<<1152, 256, 0, stream>>>(w1, w2, g1, be1, mu1, va1,
                                          g2, be2, mu2, va2, w1p, w2p, b1, b2, zp);
  conv_mfma<1><<<NBLK, 256, 0, stream>>>(xb, w1p, b1, nullptr, o1b, nullptr,
                                         (const char*)zp);
  conv_mfma<2><<<NBLK, 256, 0, stream>>>(o1b, w2p, b2, xb, nullptr, (float*)d_out,
                                         (const char*)zp);
}

// Round 6
// 358.980 us; speedup vs baseline: 1.3962x; 1.3962x over previous
//
#include <hip/hip_runtime.h>
#include <cstdint>

typedef __attribute__((ext_vector_type(8))) short bf16x8;
typedef __attribute__((ext_vector_type(4))) float f32x4;
typedef unsigned short u16;
typedef uint32_t u32;

#define HW56 56
#define HWSQ 3136       // 56*56
#define MTOT 200704     // 64*3136
#define CCH 128
#define NSTEP 18        // 9 taps * 2 K-halves (BK=64)

__device__ __forceinline__ u16 f2bf(float f) {
  u32 u = __builtin_bit_cast(u32, f);
  u = (u + 0x7fffu + ((u >> 16) & 1u)) >> 16;   // RNE
  return (u16)u;
}
__device__ __forceinline__ float bf2f(u16 h) {
  return __builtin_bit_cast(float, (u32)h << 16);
}
__device__ __forceinline__ void gload16(const void* g, void* l) {
  __builtin_amdgcn_global_load_lds((const __attribute__((address_space(1))) void*)g,
                                   (__attribute__((address_space(3))) void*)l, 16, 0, 0);
}

// ===================== PADDED-LAYOUT PATH (ws >= 122.3MB) =====================
// Activation layout xb2/o1b2: [n][hp=58][w=64][c=128] bf16.
//   hp = h+1 (hp 0 and 57 are zero halo rows); w in [56,64) zero pad columns.

// ---------- pack x: NCHW f32 -> padded NHWC bf16 ----------
__global__ __launch_bounds__(256) void pack_x_pad(const float* __restrict__ x,
                                                  u16* __restrict__ xb2) {
  __shared__ u16 t[56 * 130];                 // [w][c], stride 130 (bank-friendly)
  const int tid = threadIdx.x;
  const int lane = tid & 63, wv = tid >> 6;
  const int b = blockIdx.x;                   // 64*56 blocks, one image row each
  const int n = b / 56, h = b % 56;
  const float* src = x + ((size_t)n * CCH) * HWSQ + h * HW56;
  if (lane < 56) {
#pragma unroll
    for (int k = 0; k < 32; ++k) {            // coalesced reads over w
      const int c = wv * 32 + k;
      t[lane * 130 + c] = f2bf(src[(size_t)c * HWSQ + lane]);
    }
  }
  __syncthreads();
  u16* dst = xb2 + ((size_t)(n * 58 + h + 1) * 64) * CCH;
  const int w = tid >> 2, c0 = (tid & 3) * 32;
#pragma unroll
  for (int v4 = 0; v4 < 4; ++v4) {
    u32 vv[4];
#pragma unroll
    for (int qq = 0; qq < 4; ++qq) {
      const int c = c0 + v4 * 8 + qq * 2;
      u16 a = 0, bb = 0;
      if (w < 56) { a = t[w * 130 + c]; bb = t[w * 130 + c + 1]; }
      vv[qq] = (u32)a | ((u32)bb << 16);      // w>=56 -> zero pad cols
    }
    uint4 V; V.x = vv[0]; V.y = vv[1]; V.z = vv[2]; V.w = vv[3];
    *(uint4*)(dst + (size_t)w * CCH + c0 + v4 * 8) = V;
  }
}

// ---------- pack weights (+bias, +zero page, + optional halo-row zeroing) ----------
__global__ __launch_bounds__(256) void pack_w_kernel(
    const float* __restrict__ w1, const float* __restrict__ w2,
    const float* __restrict__ g1, const float* __restrict__ be1,
    const float* __restrict__ mu1, const float* __restrict__ va1,
    const float* __restrict__ g2, const float* __restrict__ be2,
    const float* __restrict__ mu2, const float* __restrict__ va2,
    u16* __restrict__ w1p, u16* __restrict__ w2p,
    float* __restrict__ b1, float* __restrict__ b2, float* __restrict__ zp,
    u16* __restrict__ hz1, u16* __restrict__ hz2) {
  if (blockIdx.x >= 1152) {                   // halo-zero blocks (padded path only)
    if (hz1) {
      const uint4 z4 = {0u, 0u, 0u, 0u};
      const int u = (blockIdx.x - 1152) * 256 + threadIdx.x;  // [0,65536)
#pragma unroll
      for (int k = 0; k < 2; ++k) {
        const int v = u * 2 + k;              // [0,131072) uint4 per buffer
        const int img = v >> 11;              // 2048 uint4 per image (2 rows)
        const int rr = (v >> 10) & 1;
        const int off = v & 1023;
        const size_t rowbase = ((size_t)(img * 58 + (rr ? 57 : 0)) * 64) * CCH;
        *(uint4*)(hz1 + rowbase + off * 8) = z4;
        *(uint4*)(hz2 + rowbase + off * 8) = z4;
      }
    }
    return;
  }
  const int idx = blockIdx.x * 256 + threadIdx.x;
  if (idx < 2 * 147456) {
    const int which = idx >= 147456;
    const int j = which ? idx - 147456 : idx;
    const int t = j >> 14;            // tap 0..8
    const int oc = (j >> 7) & 127;
    const int ic = j & 127;
    const float* w = which ? w2 : w1;
    const float* gg = which ? g2 : g1;
    const float* va = which ? va2 : va1;
    const float s = gg[oc] * rsqrtf(va[oc] + 1e-5f);
    const float val = w[(size_t)(oc * 128 + ic) * 9 + t] * s;
    (which ? w2p : w1p)[j] = f2bf(val);
  }
  if (blockIdx.x == 0) {
    const int t = threadIdx.x;
    if (t < 128) {
      const float s1 = g1[t] * rsqrtf(va1[t] + 1e-5f);
      b1[t] = be1[t] - mu1[t] * s1;
      const float s2 = g2[t] * rsqrtf(va2[t] + 1e-5f);
      b2[t] = be2[t] - mu2[t] * s2;
    }
    if (t < 64) zp[t] = 0.f;
  }
}

// ---------- halo-staged implicit-GEMM conv 3x3 (stage A ONCE, 9 taps from LDS) ----
// BM=256 (4 image rows x 64 padded w), 8 waves (4 row x 2 oc-half), 64x64 each.
// A: 6 padded rows (96KB) staged once, XOR-swizzled 16-slot rows of 256B.
// B: per (tap,kh) 128oc x 64k, double-buffered 2x16KB, 128B rows swizzled.
template <int PASS>
__global__ __launch_bounds__(512, 2) void conv_halo(
    const u16* __restrict__ src, const u16* __restrict__ wp,
    const float* __restrict__ bias, const u16* __restrict__ resid,
    u16* __restrict__ outb, float* __restrict__ outf) {
  __shared__ __align__(1024) char lds[256 + 98304 + 512 + 32768];  // 131,840B
  char* const Abase = lds + 256;                 // zero row sits below Abase
  char* const Bbase = lds + 256 + 98304 + 512;
  const int tid = threadIdx.x;
  const int wave = tid >> 6, lane = tid & 63;
  const int wm = wave >> 1, wn = wave & 1;       // wm: image row 0..3; wn: oc half
  const int l15 = lane & 15, q = lane >> 4;
  // T1 XCD swizzle: 896 = 8*112 bijective
  const int bid = blockIdx.x;
  const int swz = (bid & 7) * 112 + (bid >> 3);
  const int n = swz / 14, rg = swz % 14, h0 = rg * 4;

  // zero row (catches arow == -1 i.e. (h0-1, w=-1) -> zero)
  if (tid < 16) { const uint4 z4 = {0u,0u,0u,0u}; *(uint4*)(lds + tid * 16) = z4; }

  // A stage: rows hp0..hp0+5 of xb2 are CONTIGUOUS 96KB; swizzle via source XOR.
  const char* Asrc = (const char*)src + ((size_t)(n * 58 + h0) * 64) * 256;
  const u32 aswz = (((u32)tid >> 4) & 7) << 4;   // (row&7)<<4, row = d>>8
#pragma unroll
  for (int rd = 0; rd < 12; ++rd) {
    const u32 d = rd * 8192 + tid * 16;
    gload16(Asrc + (d ^ aswz), Abase + d);       // LDS dest wave-uniform+lane*16
  }

  const u32 bswz = (((u32)tid >> 3) & 7) << 4;   // (oc-row&7)<<4, row = d>>7
  auto stageB = [&](int buf, int s) {            // 2 gload16 per thread
    const int t = s >> 1, kh = s & 1;
    const char* base = (const char*)wp + t * 32768 + kh * 128;
    char* ldsB = Bbase + buf * 16384;
#pragma unroll
    for (int i = 0; i < 2; ++i) {
      const u32 d = i * 8192 + tid * 16;
      const u32 srcoff = ((d & 0xFFFFFF80u) << 1) | ((d & 0x70u) ^ bswz);
      gload16(base + srcoff, ldsB + d);
    }
  };

  f32x4 acc[4][4];
#pragma unroll
  for (int m = 0; m < 4; ++m)
#pragma unroll
    for (int nf = 0; nf < 4; ++nf) {
      f32x4 z = {0.f, 0.f, 0.f, 0.f};
      acc[m][nf] = z;
    }

  stageB(0, 0);
  __syncthreads();                               // A + B0 + zero row visible

#pragma unroll
  for (int s = 0; s < NSTEP; ++s) {
    const int t = s >> 1, kh = s & 1;
    const int dy = t / 3 - 1, dx = t % 3 - 1;
    if (s + 1 < NSTEP) stageB((s + 1) & 1, s + 1);
    const char* Bb = Bbase + (s & 1) * 16384;
    bf16x8 bfr[4][2];
#pragma unroll
    for (int nf = 0; nf < 4; ++nf) {
      const char* rp = Bb + (wn * 64 + nf * 16 + l15) * 128;
#pragma unroll
      for (int ks = 0; ks < 2; ++ks)
        bfr[nf][ks] = *(const bf16x8*)(rp + (((ks * 4 + q) ^ (lane & 7)) << 4));
    }
    bf16x8 afr[4][2];
#pragma unroll
    for (int m = 0; m < 4; ++m) {
      // staged linear row for input (h0+wm+dy, w=m*16+l15+dx); pads/zero-row
      // make all boundary cases correct without per-lane selects.
      const int arow = (wm + 1 + dy) * 64 + m * 16 + l15 + dx;
      const char* rp = Abase + arow * 256;
      const int s3 = arow & 7;
#pragma unroll
      for (int ks = 0; ks < 2; ++ks)
        afr[m][ks] = *(const bf16x8*)(rp + ((kh * 8 + ((ks * 4 + q) ^ s3)) << 4));
    }
#pragma unroll
    for (int ks = 0; ks < 2; ++ks)
#pragma unroll
      for (int m = 0; m < 4; ++m)
#pragma unroll
        for (int nf = 0; nf < 4; ++nf)
          acc[m][nf] = __builtin_amdgcn_mfma_f32_16x16x32_bf16(afr[m][ks], bfr[nf][ks],
                                                               acc[m][nf], 0, 0, 0);
    __syncthreads();                             // B dbuf hazard + drain (m97 style)
  }

  const int h = h0 + wm;
  if (PASS == 1) {
    // write padded bf16; pad cols w>=56 MUST be zero (conv2 input invariant)
    u16* orow = outb + ((size_t)(n * 58 + h + 1) * 64) * CCH;
#pragma unroll
    for (int nf = 0; nf < 4; ++nf) {
      const int oc = wn * 64 + nf * 16 + l15;
      const float bb = bias[oc];
#pragma unroll
      for (int m = 0; m < 4; ++m)
#pragma unroll
        for (int r = 0; r < 4; ++r) {
          const int w = m * 16 + q * 4 + r;
          const float v = (w < 56) ? fmaxf(acc[m][nf][r] + bb, 0.f) : 0.f;
          orow[(size_t)w * CCH + oc] = f2bf(v);
        }
    }
  } else {
    // bias + residual + relu, per-wave LDS transpose -> coalesced NCHW f32
    float* tl = (float*)(lds + wave * 4352);     // [64][17] f32, wave-private
    const u16* rrow = resid + ((size_t)(n * 58 + h + 1) * 64) * CCH;
#pragma unroll
    for (int nf = 0; nf < 4; ++nf) {
      const int oc = wn * 64 + nf * 16 + l15;
      const float bb = bias[oc];
#pragma unroll
      for (int m = 0; m < 4; ++m)
#pragma unroll
        for (int r = 0; r < 4; ++r) {
          const int w = m * 16 + q * 4 + r;
          const float rv = bf2f(rrow[(size_t)w * CCH + oc]);
          tl[w * 17 + l15] = fmaxf(acc[m][nf][r] + bb + rv, 0.f);
        }
#pragma unroll
      for (int oci = 0; oci < 16; ++oci) {
        const float v = tl[lane * 17 + oci];
        if (lane < 56)
          outf[((size_t)n * CCH + wn * 64 + nf * 16 + oci) * HWSQ + h * HW56 + lane] = v;
      }
    }
  }
}

// ===================== FALLBACK PATH (round-3, ws < 122.3MB) =====================
#define BM 128
#define NBLK (MTOT / BM)
#define NB_PER_XCD (NBLK / 8)

__global__ __launch_bounds__(256) void pack_x_kernel(const float* __restrict__ x,
                                                     u16* __restrict__ xb) {
  __shared__ u16 t[128 * 65];
  const int tid = threadIdx.x;
  const int lane = tid & 63, wv = tid >> 6;
  const int p0 = blockIdx.x * 64;
  const int n = p0 / HWSQ, hw0 = p0 % HWSQ;
  const float* src = x + (size_t)(n * CCH) * HWSQ + hw0;
#pragma unroll
  for (int k = 0; k < 32; ++k) {
    const int c = wv * 32 + k;
    t[c * 65 + lane] = f2bf(src[(size_t)c * HWSQ + lane]);
  }
  __syncthreads();
  u16* dst = xb + (size_t)p0 * CCH;
#pragma unroll
  for (int it = 0; it < 4; ++it) {
    const int u = it * 256 + tid;
    const int pos = u >> 4, ch0 = (u & 15) * 8;
    u32 vv[4];
#pragma unroll
    for (int qq = 0; qq < 4; ++qq) {
      const u16 a = t[(ch0 + 2 * qq) * 65 + pos];
      const u16 b = t[(ch0 + 2 * qq + 1) * 65 + pos];
      vv[qq] = (u32)a | ((u32)b << 16);
    }
    uint4 v; v.x = vv[0]; v.y = vv[1]; v.z = vv[2]; v.w = vv[3];
    *(uint4*)(dst + (size_t)pos * CCH + ch0) = v;
  }
}

template <int PASS>
__global__ __launch_bounds__(256, 2) void conv_mfma(
    const u16* __restrict__ src, const u16* __restrict__ wp,
    const float* __restrict__ bias, const u16* __restrict__ resid,
    u16* __restrict__ outb, float* __restrict__ outf,
    const char* __restrict__ zp) {
  __shared__ __align__(1024) char lds[65536];
  const int tid = threadIdx.x;
  const int wave = tid >> 6, lane = tid & 63;
  const int bid = blockIdx.x;
  const int swz = (bid & 7) * NB_PER_XCD + (bid >> 3);
  const int m0 = swz * BM;
  const int wm = wave >> 1, wn = wave & 1;
  const int g = lane & 7;
  int ah[4], aw[4];
  long long aoff[4], boff[4];
#pragma unroll
  for (int i = 0; i < 4; ++i) {
    const int r = wave * 32 + i * 8 + (lane >> 3);
    const int pos = m0 + r;
    const int hw = pos % HWSQ;
    ah[i] = hw / HW56;
    aw[i] = hw % HW56;
    const int gsw = g ^ (r & 7);
    aoff[i] = (long long)pos * 256 + gsw * 16;
    boff[i] = (long long)r * 256 + gsw * 16;
  }
  const char* srcb = (const char*)src;
  const char* wpb = (const char*)wp;
  auto stage = [&](int buf, int s) {
    const int t = s >> 1, kh = s & 1;
    const int dyo = t / 3 - 1, dxo = t % 3 - 1;
    const long long adelta = (long long)(dyo * HW56 + dxo) * 256 + kh * 128;
    const long long bdelta = (long long)t * 32768 + kh * 128;
    char* ldsA = lds + buf * 16384;
    char* ldsB = lds + 32768 + buf * 16384;
#pragma unroll
    for (int i = 0; i < 4; ++i) {
      const int hh = ah[i] + dyo, ww = aw[i] + dxo;
      const bool valid = ((unsigned)hh < 56u) & ((unsigned)ww < 56u);
      const char* ap = valid ? (srcb + aoff[i] + adelta) : zp;
      gload16(ap, ldsA + (wave * 32 + i * 8) * 128);
      gload16(wpb + boff[i] + bdelta, ldsB + (wave * 32 + i * 8) * 128);
    }
  };
  f32x4 acc[4][4];
#pragma unroll
  for (int m = 0; m < 4; ++m)
#pragma unroll
    for (int nf = 0; nf < 4; ++nf) {
      f32x4 z = {0.f, 0.f, 0.f, 0.f};
      acc[m][nf] = z;
    }
  auto compute = [&](int buf) {
    const char* ldsA = lds + buf * 16384;
    const char* ldsB = lds + 32768 + buf * 16384;
    bf16x8 a[4][2], b[4][2];
#pragma unroll
    for (int m = 0; m < 4; ++m) {
      const int row = wm * 64 + m * 16 + (lane & 15);
      const char* rp = ldsA + row * 128;
      const int sw = row & 7;
#pragma unroll
      for (int ks = 0; ks < 2; ++ks) {
        const int gg = ks * 4 + (lane >> 4);
        a[m][ks] = *(const bf16x8*)(rp + ((gg ^ sw) << 4));
      }
    }
#pragma unroll
    for (int nf = 0; nf < 4; ++nf) {
      const int row = wn * 64 + nf * 16 + (lane & 15);
      const char* rp = ldsB + row * 128;
      const int sw = row & 7;
#pragma unroll
      for (int ks = 0; ks < 2; ++ks) {
        const int gg = ks * 4 + (lane >> 4);
        b[nf][ks] = *(const bf16x8*)(rp + ((gg ^ sw) << 4));
      }
    }
#pragma unroll
    for (int ks = 0; ks < 2; ++ks)
#pragma unroll
      for (int m = 0; m < 4; ++m)
#pragma unroll
        for (int nf = 0; nf < 4; ++nf)
          acc[m][nf] = __builtin_amdgcn_mfma_f32_16x16x32_bf16(a[m][ks], b[nf][ks],
                                                               acc[m][nf], 0, 0, 0);
  };
  stage(0, 0);
  __syncthreads();
#pragma unroll
  for (int s = 0; s < NSTEP; ++s) {
    const int cur = s & 1;
    if (s + 1 < NSTEP) stage(cur ^ 1, s + 1);
    compute(cur);
    __syncthreads();
  }
  if (PASS == 1) {
#pragma unroll
    for (int nf = 0; nf < 4; ++nf) {
      const int oc = wn * 64 + nf * 16 + (lane & 15);
      const float bb = bias[oc];
#pragma unroll
      for (int m = 0; m < 4; ++m) {
        const int pbase = m0 + wm * 64 + m * 16 + (lane >> 4) * 4;
#pragma unroll
        for (int r = 0; r < 4; ++r) {
          float v = acc[m][nf][r] + bb;
          v = fmaxf(v, 0.f);
          outb[(size_t)(pbase + r) * CCH + oc] = f2bf(v);
        }
      }
    }
  } else {
    float* tl = (float*)(lds + wave * 4352);
    const int posr = m0 + wm * 64 + lane;
    const int nimg = posr / HWSQ, hwr = posr % HWSQ;
#pragma unroll
    for (int nf = 0; nf < 4; ++nf) {
      const int oc = wn * 64 + nf * 16 + (lane & 15);
      const float bb = bias[oc];
#pragma unroll
      for (int m = 0; m < 4; ++m) {
#pragma unroll
        for (int r = 0; r < 4; ++r) {
          const int row = m * 16 + (lane >> 4) * 4 + r;
          const int pos = m0 + wm * 64 + row;
          const float rv = bf2f(resid[(size_t)pos * CCH + oc]);
          float v = acc[m][nf][r] + bb + rv;
          tl[row * 17 + (lane & 15)] = fmaxf(v, 0.f);
        }
      }
#pragma unroll
      for (int oci = 0; oci < 16; ++oci) {
        const float v = tl[lane * 17 + oci];
        const int oc2 = wn * 64 + nf * 16 + oci;
        outf[(size_t)(nimg * CCH + oc2) * HWSQ + hwr] = v;
      }
    }
  }
}

extern "C" void kernel_launch(void* const* d_in, const int* in_sizes, int n_in,
                              void* d_out, int out_size, void* d_ws, size_t ws_size,
                              hipStream_t stream) {
  const float* x = (const float*)d_in[0];
  const float* w1 = (const float*)d_in[1];
  const float* w2 = (const float*)d_in[2];
  const float* g1 = (const float*)d_in[3];
  const float* be1 = (const float*)d_in[4];
  const float* mu1 = (const float*)d_in[5];
  const float* va1 = (const float*)d_in[6];
  const float* g2 = (const float*)d_in[7];
  const float* be2 = (const float*)d_in[8];
  const float* mu2 = (const float*)d_in[9];
  const float* va2 = (const float*)d_in[10];

  char* ws = (char*)d_ws;
  const size_t PADSZ = (size_t)64 * 58 * 64 * 128 * 2;   // 60,817,408 per buffer

  if (ws_size >= 2 * PADSZ + 2 * 294912 + 2048) {
    // ---- padded halo path ----
    u16* xb2  = (u16*)(ws + 0);
    u16* o1b2 = (u16*)(ws + PADSZ);
    u16* w1p  = (u16*)(ws + 2 * PADSZ);
    u16* w2p  = (u16*)(ws + 2 * PADSZ + 294912);
    float* b1 = (float*)(ws + 2 * PADSZ + 2 * 294912);
    float* b2 = (float*)(ws + 2 * PADSZ + 2 * 294912 + 512);
    float* zp = (float*)(ws + 2 * PADSZ + 2 * 294912 + 1024);

    pack_x_pad<<<64 * 56, 256, 0, stream>>>(x, xb2);
    pack_w_kernel<<<1152 + 256, 256, 0, stream>>>(w1, w2, g1, be1, mu1, va1,
                                                  g2, be2, mu2, va2, w1p, w2p,
                                                  b1, b2, zp, xb2, o1b2);
    conv_halo<1><<<896, 512, 0, stream>>>(xb2, w1p, b1, nullptr, o1b2, nullptr);
    conv_halo<2><<<896, 512, 0, stream>>>(o1b2, w2p, b2, xb2, nullptr, (float*)d_out);
  } else {
    // ---- round-3 fallback ----
    u16* xb  = (u16*)(ws + 0);
    u16* o1b = (u16*)(ws + 51380224);
    u16* w1p = (u16*)(ws + 102760448);
    u16* w2p = (u16*)(ws + 103055360);
    float* b1 = (float*)(ws + 103350272);
    float* b2 = (float*)(ws + 103350784);
    float* zp = (float*)(ws + 103351296);

    pack_x_kernel<<<MTOT / 64, 256, 0, stream>>>(x, xb);
    pack_w_kernel<<<1152, 256, 0, stream>>>(w1, w2, g1, be1, mu1, va1,
                                            g2, be2, mu2, va2, w1p, w2p,
                                            b1, b2, zp, nullptr, nullptr);
    conv_mfma<1><<<NBLK, 256, 0, stream>>>(xb, w1p, b1, nullptr, o1b, nullptr,
                                           (const char*)zp);
    conv_mfma<2><<<NBLK, 256, 0, stream>>>(o1b, w2p, b2, xb, nullptr, (float*)d_out,
                                           (const char*)zp);
  }
}

// Round 8
// 355.547 us; speedup vs baseline: 1.4096x; 1.0097x over previous
//
#include <hip/hip_runtime.h>
#include <cstdint>

typedef __attribute__((ext_vector_type(8))) short bf16x8;
typedef __attribute__((ext_vector_type(4))) float f32x4;
typedef unsigned short u16;
typedef uint32_t u32;

#define HW56 56
#define HWSQ 3136       // 56*56
#define MTOT 200704     // 64*3136
#define CCH 128
#define BM 128
#define NSTEP 36        // 9 taps * 4 K-quarters (BK=32)
#define NBLK (MTOT / BM)        // 1568 = 8 * 196
#define NB_PER_XCD (NBLK / 8)   // 196

__device__ __forceinline__ u16 f2bf(float f) {
  u32 u = __builtin_bit_cast(u32, f);
  u = (u + 0x7fffu + ((u >> 16) & 1u)) >> 16;   // RNE
  return (u16)u;
}
__device__ __forceinline__ float bf2f(u16 h) {
  return __builtin_bit_cast(float, (u32)h << 16);
}
__device__ __forceinline__ void gload16(const void* g, void* l) {
  __builtin_amdgcn_global_load_lds((const __attribute__((address_space(1))) void*)g,
                                   (__attribute__((address_space(3))) void*)l, 16, 0, 0);
}

// ---------- pack x: NCHW f32 -> NHWC bf16, LDS-transposed so BOTH sides coalesce ----
__global__ __launch_bounds__(256) void pack_x_kernel(const float* __restrict__ x,
                                                     u16* __restrict__ xb) {
  __shared__ u16 t[128 * 65];                 // [c][pos], stride 65 (bank-friendly)
  const int tid = threadIdx.x;
  const int lane = tid & 63, wv = tid >> 6;
  const int p0 = blockIdx.x * 64;             // 64 pos, one image (3136 % 64 == 0)
  const int n = p0 / HWSQ, hw0 = p0 % HWSQ;
  const float* src = x + (size_t)(n * CCH) * HWSQ + hw0;
#pragma unroll
  for (int k = 0; k < 32; ++k) {              // coalesced 256B reads per instr
    const int c = wv * 32 + k;
    t[c * 65 + lane] = f2bf(src[(size_t)c * HWSQ + lane]);
  }
  __syncthreads();
  u16* dst = xb + (size_t)p0 * CCH;
#pragma unroll
  for (int it = 0; it < 4; ++it) {            // coalesced 1KB writes per wave-instr
    const int u = it * 256 + tid;
    const int pos = u >> 4, ch0 = (u & 15) * 8;
    u32 vv[4];
#pragma unroll
    for (int q = 0; q < 4; ++q) {
      const u16 a = t[(ch0 + 2 * q) * 65 + pos];
      const u16 b = t[(ch0 + 2 * q + 1) * 65 + pos];
      vv[q] = (u32)a | ((u32)b << 16);
    }
    uint4 v; v.x = vv[0]; v.y = vv[1]; v.z = vv[2]; v.w = vv[3];
    *(uint4*)(dst + (size_t)pos * CCH + ch0) = v;
  }
}

// ---------- pack weights: fold BN scale, [O][I][3][3] f32 -> [tap][oc][ic] bf16 ----------
__global__ __launch_bounds__(256) void pack_w_kernel(
    const float* __restrict__ w1, const float* __restrict__ w2,
    const float* __restrict__ g1, const float* __restrict__ be1,
    const float* __restrict__ mu1, const float* __restrict__ va1,
    const float* __restrict__ g2, const float* __restrict__ be2,
    const float* __restrict__ mu2, const float* __restrict__ va2,
    u16* __restrict__ w1p, u16* __restrict__ w2p,
    float* __restrict__ b1, float* __restrict__ b2, float* __restrict__ zp) {
  const int idx = blockIdx.x * 256 + threadIdx.x;   // grid = 294912/256
  if (idx < 2 * 147456) {
    const int which = idx >= 147456;
    const int j = which ? idx - 147456 : idx;
    const int t = j >> 14;            // tap 0..8
    const int oc = (j >> 7) & 127;
    const int ic = j & 127;
    const float* w = which ? w2 : w1;
    const float* gg = which ? g2 : g1;
    const float* va = which ? va2 : va1;
    const float s = gg[oc] * rsqrtf(va[oc] + 1e-5f);
    const float val = w[(size_t)(oc * 128 + ic) * 9 + t] * s;
    (which ? w2p : w1p)[j] = f2bf(val);
  }
  if (blockIdx.x == 0) {
    const int t = threadIdx.x;
    if (t < 128) {
      const float s1 = g1[t] * rsqrtf(va1[t] + 1e-5f);
      b1[t] = be1[t] - mu1[t] * s1;
      const float s2 = g2[t] * rsqrtf(va2[t] + 1e-5f);
      b2[t] = be2[t] - mu2[t] * s2;
    }
    if (t < 64) zp[t] = 0.f;          // 256B zero page (ws is re-poisoned each launch)
  }
}

// ---------- implicit-GEMM conv 3x3 (pad=1) with fused BN(+ReLU)(+residual) ----------
// Round-3 structure with BK=32: LDS 32KB/block -> 4 blocks/CU resident, so the
// per-step barrier drain overlaps with 3 other blocks' compute (m114 mechanism).
// LDS: A0|A1|B0|B1, 8KB each. Rows of 64B (32 ic bf16), 4 slots of 16B;
// slot g of row r holds source 16B-group g^(r&3).
template <int PASS>
__global__ __launch_bounds__(256, 4) void conv_mfma(
    const u16* __restrict__ src, const u16* __restrict__ wp,
    const float* __restrict__ bias, const u16* __restrict__ resid,
    u16* __restrict__ outb, float* __restrict__ outf,
    const char* __restrict__ zp) {
  __shared__ __align__(1024) char lds[32768];
  const int tid = threadIdx.x;
  const int wave = tid >> 6, lane = tid & 63;
  const int l15 = lane & 15, q = lane >> 4;
  // T1: XCD-chunked bijective swizzle (1568 % 8 == 0)
  const int bid = blockIdx.x;
  const int swz = (bid & 7) * NB_PER_XCD + (bid >> 3);
  const int m0 = swz * BM;
  const int wm = wave >> 1, wn = wave & 1;    // 2x2 wave grid, 64x64 tile each

  // Staging state: 2 rows per thread (r = i*64 + tid>>2), one 16B group each.
  const int g = tid & 3;
  int ah[2], aw[2];
  long long aoff[2], boff[2];
#pragma unroll
  for (int i = 0; i < 2; ++i) {
    const int r = i * 64 + (tid >> 2);              // row 0..127
    const int pos = m0 + r;
    const int hw = pos % HWSQ;
    ah[i] = hw / HW56;
    aw[i] = hw % HW56;
    const int gsw = g ^ (r & 3);                    // pre-swizzled source group
    aoff[i] = (long long)pos * 256 + gsw * 16;      // NHWC row = 256B
    boff[i] = (long long)r * 256 + gsw * 16;        // w row (oc) = 256B
  }
  const char* srcb = (const char*)src;
  const char* wpb = (const char*)wp;

  auto stage = [&](int buf, int s) {                // 4 gload16 per thread
    const int t = s >> 2, kh2 = s & 3;
    const int dyo = t / 3 - 1, dxo = t % 3 - 1;
    const long long adelta = (long long)(dyo * HW56 + dxo) * 256 + kh2 * 64;
    const long long bdelta = (long long)t * 32768 + kh2 * 64;
    char* ldsA = lds + buf * 8192;
    char* ldsB = lds + 16384 + buf * 8192;
#pragma unroll
    for (int i = 0; i < 2; ++i) {
      const int hh = ah[i] + dyo, ww = aw[i] + dxo;
      const bool valid = ((unsigned)hh < 56u) & ((unsigned)ww < 56u);
      const char* ap = valid ? (srcb + aoff[i] + adelta) : zp;  // zero-pad via zero page
      gload16(ap, ldsA + i * 4096 + wave * 1024);               // dest wave-uniform
      gload16(wpb + boff[i] + bdelta, ldsB + i * 4096 + wave * 1024);
    }
  };

  f32x4 acc[4][4];
#pragma unroll
  for (int m = 0; m < 4; ++m)
#pragma unroll
    for (int n = 0; n < 4; ++n) {
      f32x4 z = {0.f, 0.f, 0.f, 0.f};
      acc[m][n] = z;
    }

  auto compute = [&](int buf) {
    const char* ldsA = lds + buf * 8192;
    const char* ldsB = lds + 16384 + buf * 8192;
    bf16x8 a[4], b[4];
#pragma unroll
    for (int m = 0; m < 4; ++m) {
      const int row = wm * 64 + m * 16 + l15;
      a[m] = *(const bf16x8*)(ldsA + row * 64 + ((q ^ (row & 3)) << 4));
    }
#pragma unroll
    for (int n = 0; n < 4; ++n) {
      const int row = wn * 64 + n * 16 + l15;
      b[n] = *(const bf16x8*)(ldsB + row * 64 + ((q ^ (row & 3)) << 4));
    }
#pragma unroll
    for (int m = 0; m < 4; ++m)
#pragma unroll
      for (int n = 0; n < 4; ++n)
        acc[m][n] = __builtin_amdgcn_mfma_f32_16x16x32_bf16(a[m], b[n],
                                                            acc[m][n], 0, 0, 0);
  };

  stage(0, 0);
  __syncthreads();
#pragma unroll
  for (int s = 0; s < NSTEP; ++s) {
    const int cur = s & 1;
    if (s + 1 < NSTEP) stage(cur ^ 1, s + 1);   // prefetch next tile into other buffer
    compute(cur);
    __syncthreads();                             // drains vmcnt+lgkmcnt (m97 structure)
  }

  if (PASS == 1) {
#pragma unroll
    for (int nf = 0; nf < 4; ++nf) {
      const int oc = wn * 64 + nf * 16 + l15;
      const float bb = bias[oc];
#pragma unroll
      for (int m = 0; m < 4; ++m) {
        const int pbase = m0 + wm * 64 + m * 16 + q * 4;
#pragma unroll
        for (int r = 0; r < 4; ++r) {
          float v = acc[m][nf][r] + bb;
          v = fmaxf(v, 0.f);
          outb[(size_t)(pbase + r) * CCH + oc] = f2bf(v);
        }
      }
    }
  } else {
    // epilogue: bias + residual + relu, then per-wave LDS transpose -> coalesced NCHW f32
    float* tl = (float*)(lds + wave * 4352);     // [64][17] f32, wave-private
    const int posr = m0 + wm * 64 + lane;
    const int nimg = posr / HWSQ, hwr = posr % HWSQ;
#pragma unroll
    for (int nf = 0; nf < 4; ++nf) {
      const int oc = wn * 64 + nf * 16 + l15;
      const float bb = bias[oc];
#pragma unroll
      for (int m = 0; m < 4; ++m) {
#pragma unroll
        for (int r = 0; r < 4; ++r) {
          const int row = m * 16 + q * 4 + r;
          const int pos = m0 + wm * 64 + row;
          const float rv = bf2f(resid[(size_t)pos * CCH + oc]);
          float v = acc[m][nf][r] + bb + rv;
          tl[row * 17 + l15] = fmaxf(v, 0.f);
        }
      }
      // compiler inserts lgkmcnt waits for the within-wave LDS RAW/WAR here
#pragma unroll
      for (int oci = 0; oci < 16; ++oci) {
        const float v = tl[lane * 17 + oci];
        const int oc2 = wn * 64 + nf * 16 + oci;
        outf[(size_t)(nimg * CCH + oc2) * HWSQ + hwr] = v;   // 64 consecutive hw per store
      }
    }
  }
}

extern "C" void kernel_launch(void* const* d_in, const int* in_sizes, int n_in,
                              void* d_out, int out_size, void* d_ws, size_t ws_size,
                              hipStream_t stream) {
  const float* x = (const float*)d_in[0];
  const float* w1 = (const float*)d_in[1];
  const float* w2 = (const float*)d_in[2];
  const float* g1 = (const float*)d_in[3];
  const float* be1 = (const float*)d_in[4];
  const float* mu1 = (const float*)d_in[5];
  const float* va1 = (const float*)d_in[6];
  const float* g2 = (const float*)d_in[7];
  const float* be2 = (const float*)d_in[8];
  const float* mu2 = (const float*)d_in[9];
  const float* va2 = (const float*)d_in[10];

  char* ws = (char*)d_ws;
  u16* xb  = (u16*)(ws + 0);                    // 200704*128*2 = 51,380,224 B
  u16* o1b = (u16*)(ws + 51380224);             // 51,380,224 B
  u16* w1p = (u16*)(ws + 102760448);            // 294,912 B
  u16* w2p = (u16*)(ws + 103055360);            // 294,912 B
  float* b1 = (float*)(ws + 103350272);         // 512 B
  float* b2 = (float*)(ws + 103350784);         // 512 B
  float* zp = (float*)(ws + 103351296);         // 256 B zero page

  pack_x_kernel<<<MTOT / 64, 256, 0, stream>>>(x, xb);
  pack_w_kernel<<<1152, 256, 0, stream>>>(w1, w2, g1, be1, mu1, va1,
                                          g2, be2, mu2, va2, w1p, w2p, b1, b2, zp);
  conv_mfma<1><<<NBLK, 256, 0, stream>>>(xb, w1p, b1, nullptr, o1b, nullptr,
                                         (const char*)zp);
  conv_mfma<2><<<NBLK, 256, 0, stream>>>(o1b, w2p, b2, xb, nullptr, (float*)d_out,
                                         (const char*)zp);
}